// Round 4
// baseline (480.512 us; speedup 1.0000x reference)
//
#include <hip/hip_runtime.h>

// Problem constants (B,C,H,W) = (8,32,512,512), K=9
#define HH 512
#define WW 512
#define SEGS 16
#define SEGROWS 32   // HH / SEGS
#define CG 128       // float4 column-groups per row (WW/4)

__device__ __forceinline__ int imax(int a, int b) { return a > b ? a : b; }
__device__ __forceinline__ int imin(int a, int b) { return a < b ? a : b; }

// out = (1/8) * [ sum (81 + ch(h)*cw(w)) * x^2  -  2 * sum RowBox9(x) * ColBox9(x) ]
// Software-pipelined: loads for row i+2 issued before computing row i, so each
// wave keeps >=6 loads in flight (covers ~900cyc HBM latency across waves).
__global__ __launch_bounds__(256, 4) void scc_kernel(const float* __restrict__ img,
                                                     float* __restrict__ out) {
    const int tid   = blockIdx.x * 256 + threadIdx.x;
    const int g     = tid & (CG - 1);      // column group: cols [4g, 4g+3]
    const int rest  = tid >> 7;
    const int seg   = rest & (SEGS - 1);   // wave-uniform
    const int plane = rest >> 4;           // wave-uniform

    const float* base = img + (size_t)plane * (HH * WW);
    const int r0 = seg * SEGROWS;

    // per-column border weight cw(w) = #valid horizontal window positions
    float4 cw;
    {
        int w0 = 4 * g;
        cw.x = (float)(9 - imax(0, 4 - (w0 + 0)) - imax(0, (w0 + 0) - (WW - 5)));
        cw.y = (float)(9 - imax(0, 4 - (w0 + 1)) - imax(0, (w0 + 1) - (WW - 5)));
        cw.z = (float)(9 - imax(0, 4 - (w0 + 2)) - imax(0, (w0 + 2) - (WW - 5)));
        cw.w = (float)(9 - imax(0, 4 - (w0 + 3)) - imax(0, (w0 + 3) - (WW - 5)));
    }

    // clamped neighbor offsets (bytes) + 0/1 edge masks, computed once
    const int offL = imax(g - 1, 0) * 16;
    const int offC = g * 16;
    const int offR = imin(g + 1, CG - 1) * 16;
    const float mL = (g > 0) ? 1.f : 0.f;
    const float mR = (g < CG - 1) ? 1.f : 0.f;

    const float4 z4 = make_float4(0.f, 0.f, 0.f, 0.f);
    // x-ring: x0..x8 = x(r-9 .. r-1) before the shift of streamed row r
    float4 x0 = z4, x1 = z4, x2 = z4, x3 = z4, x4 = z4,
           x5 = z4, x6 = z4, x7 = z4, x8 = z4;
    // R-ring: q0..q4 = R(r-5 .. r-1) before shift
    float4 q0 = z4, q1 = z4, q2 = z4, q3 = z4, q4 = z4;
    float4 V = z4;             // after update: sum x(r-8 .. r)
    float accW = 0.f, accRV = 0.f;

    auto ldrow = [&](int i, float4& L, float4& C, float4& R, float& m) {
        const int r   = r0 - 4 + i;                 // streamed row (may be OOB)
        const int rcl = imin(imax(r, 0), HH - 1);   // clamped, wave-uniform
        m = ((unsigned)r < (unsigned)HH) ? 1.f : 0.f;
        const char* rowb = (const char*)(base + (ptrdiff_t)rcl * WW);
        L = *(const float4*)(rowb + offL);
        C = *(const float4*)(rowb + offC);
        R = *(const float4*)(rowb + offR);
    };

    auto proc = [&](float4 Lr, float4 Cr, float4 Rr, float m, bool do_acc, int i) {
        const float a = mL * m, b = mR * m;
        float4 lc = make_float4(Lr.x * a, Lr.y * a, Lr.z * a, Lr.w * a);
        float4 cc = make_float4(Cr.x * m, Cr.y * m, Cr.z * m, Cr.w * m);
        float4 rc = make_float4(Rr.x * b, Rr.y * b, Rr.z * b, Rr.w * b);

        // sliding horizontal 9-sums for the 4 owned columns
        float R0 = ((lc.x + lc.y) + (lc.z + lc.w)) + ((cc.x + cc.y) + (cc.z + cc.w)) + rc.x;
        float R1 = R0 - lc.x + rc.y;
        float R2 = R1 - lc.y + rc.z;
        float R3 = R2 - lc.z + rc.w;
        float4 Rn = make_float4(R0, R1, R2, R3);

        // running vertical 9-sum: V = sum x(r-8..r)
        V.x += cc.x - x0.x;  V.y += cc.y - x0.y;
        V.z += cc.z - x0.z;  V.w += cc.w - x0.w;

        // shift rings (renamed away by unrolling)
        x0 = x1; x1 = x2; x2 = x3; x3 = x4; x4 = x5;
        x5 = x6; x6 = x7; x7 = x8; x8 = cc;
        q0 = q1; q1 = q2; q2 = q3; q3 = q4; q4 = Rn;
        // now x0..x8 = x(r-8..r) -> center x = x4 = x(r-4); q0 = R(r-4)

        if (do_acc) {
            const int h = r0 + i - 8;   // center row, always in [0, HH)
            const float chf = (float)(9 - imax(0, 4 - h) - imax(0, h - (HH - 5)));
            float w0 = fmaf(chf, cw.x, 81.f);
            float w1 = fmaf(chf, cw.y, 81.f);
            float w2 = fmaf(chf, cw.z, 81.f);
            float w3 = fmaf(chf, cw.w, 81.f);
            accW = fmaf(w0 * x4.x, x4.x, accW);
            accW = fmaf(w1 * x4.y, x4.y, accW);
            accW = fmaf(w2 * x4.z, x4.z, accW);
            accW = fmaf(w3 * x4.w, x4.w, accW);
            accRV = fmaf(q0.x, V.x, accRV);
            accRV = fmaf(q0.y, V.y, accRV);
            accRV = fmaf(q0.z, V.z, accRV);
            accRV = fmaf(q0.w, V.w, accRV);
        }
    };

    // prime the 2-row pipeline
    float4 aL, aC, aR, bL, bC, bR;
    float am, bm;
    ldrow(0, aL, aC, aR, am);
    ldrow(1, bL, bC, bR, bm);

    // warmup rows 0..7 (fill rings, no accumulate)
#pragma unroll
    for (int i = 0; i < 8; i += 2) {
        float4 nL, nC, nR; float nm;
        ldrow(i + 2, nL, nC, nR, nm);
        proc(aL, aC, aR, am, false, i);
        aL = nL; aC = nC; aR = nR; am = nm;
        ldrow(i + 3, nL, nC, nR, nm);
        proc(bL, bC, bR, bm, false, i + 1);
        bL = nL; bC = nC; bR = nR; bm = nm;
    }
    // main rows 8..39 (32 centers); prefetch overruns are clamped+masked
#pragma unroll 4
    for (int i = 8; i < SEGROWS + 8; i += 2) {
        float4 nL, nC, nR; float nm;
        ldrow(i + 2, nL, nC, nR, nm);
        proc(aL, aC, aR, am, true, i);
        aL = nL; aC = nC; aR = nR; am = nm;
        ldrow(i + 3, nL, nC, nR, nm);
        proc(bL, bC, bR, bm, true, i + 1);
        bL = nL; bC = nC; bR = nR; bm = nm;
    }

    float acc = accW - 2.f * accRV;

    // reduce: wave64 shuffle -> LDS -> one atomic per block
#pragma unroll
    for (int off = 32; off > 0; off >>= 1)
        acc += __shfl_xor(acc, off, 64);
    __shared__ float wsum[4];
    const int lane = threadIdx.x & 63;
    const int wv   = threadIdx.x >> 6;
    if (lane == 0) wsum[wv] = acc;
    __syncthreads();
    if (threadIdx.x == 0) {
        float s = (wsum[0] + wsum[1]) + (wsum[2] + wsum[3]);
        atomicAdd(out, 0.125f * s);  // mean over batch (B = 8)
    }
}

extern "C" void kernel_launch(void* const* d_in, const int* in_sizes, int n_in,
                              void* d_out, int out_size, void* d_ws, size_t ws_size,
                              hipStream_t stream) {
    const float* img = (const float*)d_in[0];
    float* out = (float*)d_out;
    hipMemsetAsync(out, 0, sizeof(float), stream);  // d_out is poisoned 0xAA
    // 524288 work items: 256 planes x 16 row-segments x 128 column-groups
    scc_kernel<<<dim3(2048), dim3(256), 0, stream>>>(img, out);
}

// Round 5
// 397.431 us; speedup vs baseline: 1.2090x; 1.2090x over previous
//
#include <hip/hip_runtime.h>

// Problem constants (B,C,H,W) = (8,32,512,512), K=9
#define HH 512
#define WW 512
#define SEGS 16
#define SEGROWS 32   // HH / SEGS
#define CG 128       // float4 column-groups per row (WW/4)

__device__ __forceinline__ int imax(int a, int b) { return a > b ? a : b; }
__device__ __forceinline__ int imin(int a, int b) { return a < b ? a : b; }

// out = (1/8) * [ sum (81 + ch(h)*cw(w)) * x^2  -  2 * sum RowBox9(x) * ColBox9(x) ]
// Register-lean streaming: NO x-ring. Center x(r-4) and leaving-row x(r-9)
// are RE-LOADED (L1/L2 hits - their lines were fetched 4/9 rows ago).
// Live state ~55 VGPRs -> fits the compiler's 64-VGPR / 8-waves-per-EU
// preference with zero spill (round-4 lesson: don't fight the allocator).
__global__ __launch_bounds__(256) void scc_kernel(const float* __restrict__ img,
                                                  float* __restrict__ out) {
    const int tid   = blockIdx.x * 256 + threadIdx.x;
    const int g     = tid & (CG - 1);      // column group: cols [4g, 4g+3]
    const int rest  = tid >> 7;
    const int seg   = rest & (SEGS - 1);   // wave-uniform
    const int plane = rest >> 4;           // wave-uniform

    const float* base = img + (size_t)plane * (HH * WW);
    const int r0 = seg * SEGROWS;

    // per-column border weight cw(w) = #valid horizontal window positions
    float4 cw;
    {
        int w0 = 4 * g;
        cw.x = (float)(9 - imax(0, 4 - (w0 + 0)) - imax(0, (w0 + 0) - (WW - 5)));
        cw.y = (float)(9 - imax(0, 4 - (w0 + 1)) - imax(0, (w0 + 1) - (WW - 5)));
        cw.z = (float)(9 - imax(0, 4 - (w0 + 2)) - imax(0, (w0 + 2) - (WW - 5)));
        cw.w = (float)(9 - imax(0, 4 - (w0 + 3)) - imax(0, (w0 + 3) - (WW - 5)));
    }

    // clamped neighbor offsets (bytes) + 0/1 edge masks, computed once
    const int offL = imax(g - 1, 0) * 16;
    const int offC = g * 16;
    const int offR = imin(g + 1, CG - 1) * 16;
    const float mL = (g > 0) ? 1.f : 0.f;
    const float mR = (g < CG - 1) ? 1.f : 0.f;

    const float4 z4 = make_float4(0.f, 0.f, 0.f, 0.f);
    // R-ring only: after shift+push, q0 = R(r-4)
    float4 q0 = z4, q1 = z4, q2 = z4, q3 = z4, q4 = z4;
    float4 V = z4;             // running sum of last 9 masked rows
    float accW = 0.f, accRV = 0.f;

    // ---- warmup: stream rows r0-4 .. r0+3 (fill q-ring and V; no centers) ----
#pragma unroll
    for (int i = 0; i < 8; ++i) {
        const int r   = r0 - 4 + i;                // may be < 0 (seg 0 only)
        const int rcl = imax(r, 0);
        const float m = (r >= 0) ? 1.f : 0.f;
        const char* rowb = (const char*)(base + (ptrdiff_t)rcl * WW);
        float4 L = *(const float4*)(rowb + offL);
        float4 C = *(const float4*)(rowb + offC);
        float4 Rv = *(const float4*)(rowb + offR);
        const float a = mL * m, b = mR * m;
        float4 lc = make_float4(L.x * a, L.y * a, L.z * a, L.w * a);
        float4 cc = make_float4(C.x * m, C.y * m, C.z * m, C.w * m);
        float4 rc = make_float4(Rv.x * b, Rv.y * b, Rv.z * b, Rv.w * b);
        float R0 = ((lc.x + lc.y) + (lc.z + lc.w)) + ((cc.x + cc.y) + (cc.z + cc.w)) + rc.x;
        float R1 = R0 - lc.x + rc.y;
        float R2 = R1 - lc.y + rc.z;
        float R3 = R2 - lc.z + rc.w;
        V.x += cc.x; V.y += cc.y; V.z += cc.z; V.w += cc.w;
        q0 = q1; q1 = q2; q2 = q3; q3 = q4; q4 = make_float4(R0, R1, R2, R3);
    }

    // ---- main: stream rows r0+4 .. r0+35; each completes center h = r-4 ----
#pragma unroll 4
    for (int i = 8; i < SEGROWS + 8; ++i) {
        const int r   = r0 - 4 + i;                // r in [r0+4, r0+35]; >= 4
        const int rcl = imin(r, HH - 1);           // upper clamp only
        const float m = (r < HH) ? 1.f : 0.f;      // wave-uniform
        const int rm9 = r - 9;                     // leaving row
        const int r9c = imax(rm9, 0);
        const float ms = (i >= 9 && rm9 >= 0) ? 1.f : 0.f;  // only rows we added
        const int h = r - 4;                       // center row, always in-bounds

        const char* rowb = (const char*)(base + (ptrdiff_t)rcl * WW);
        float4 L  = *(const float4*)(rowb + offL);
        float4 C  = *(const float4*)(rowb + offC);
        float4 Rv = *(const float4*)(rowb + offR);
        // re-loads (L1/L2 hits: fetched 9 and 4 rows ago by this thread)
        float4 C9 = *(const float4*)((const char*)(base + (ptrdiff_t)r9c * WW) + offC);
        float4 Ch = *(const float4*)((const char*)(base + (ptrdiff_t)h   * WW) + offC);

        const float a = mL * m, b = mR * m;
        float4 lc = make_float4(L.x * a, L.y * a, L.z * a, L.w * a);
        float4 cc = make_float4(C.x * m, C.y * m, C.z * m, C.w * m);
        float4 rc = make_float4(Rv.x * b, Rv.y * b, Rv.z * b, Rv.w * b);

        // sliding horizontal 9-sums for the 4 owned columns
        float R0 = ((lc.x + lc.y) + (lc.z + lc.w)) + ((cc.x + cc.y) + (cc.z + cc.w)) + rc.x;
        float R1 = R0 - lc.x + rc.y;
        float R2 = R1 - lc.y + rc.z;
        float R3 = R2 - lc.z + rc.w;

        // V <- sum of masked rows r-8..r
        V.x += cc.x - C9.x * ms;  V.y += cc.y - C9.y * ms;
        V.z += cc.z - C9.z * ms;  V.w += cc.w - C9.w * ms;

        q0 = q1; q1 = q2; q2 = q3; q3 = q4; q4 = make_float4(R0, R1, R2, R3);
        // now q0 = R(h)

        const float chf = (float)(9 - imax(0, 4 - h) - imax(0, h - (HH - 5)));
        float w0 = fmaf(chf, cw.x, 81.f);
        float w1 = fmaf(chf, cw.y, 81.f);
        float w2 = fmaf(chf, cw.z, 81.f);
        float w3 = fmaf(chf, cw.w, 81.f);
        accW = fmaf(w0 * Ch.x, Ch.x, accW);
        accW = fmaf(w1 * Ch.y, Ch.y, accW);
        accW = fmaf(w2 * Ch.z, Ch.z, accW);
        accW = fmaf(w3 * Ch.w, Ch.w, accW);
        accRV = fmaf(q0.x, V.x, accRV);
        accRV = fmaf(q0.y, V.y, accRV);
        accRV = fmaf(q0.z, V.z, accRV);
        accRV = fmaf(q0.w, V.w, accRV);
    }

    float acc = accW - 2.f * accRV;

    // reduce: wave64 shuffle -> LDS -> one atomic per block
#pragma unroll
    for (int off = 32; off > 0; off >>= 1)
        acc += __shfl_xor(acc, off, 64);
    __shared__ float wsum[4];
    const int lane = threadIdx.x & 63;
    const int wv   = threadIdx.x >> 6;
    if (lane == 0) wsum[wv] = acc;
    __syncthreads();
    if (threadIdx.x == 0) {
        float s = (wsum[0] + wsum[1]) + (wsum[2] + wsum[3]);
        atomicAdd(out, 0.125f * s);  // mean over batch (B = 8)
    }
}

extern "C" void kernel_launch(void* const* d_in, const int* in_sizes, int n_in,
                              void* d_out, int out_size, void* d_ws, size_t ws_size,
                              hipStream_t stream) {
    const float* img = (const float*)d_in[0];
    float* out = (float*)d_out;
    hipMemsetAsync(out, 0, sizeof(float), stream);  // d_out is poisoned 0xAA
    // 524288 work items: 256 planes x 16 row-segments x 128 column-groups
    scc_kernel<<<dim3(2048), dim3(256), 0, stream>>>(img, out);
}